// Round 8
// baseline (307.454 us; speedup 1.0000x reference)
//
#include <hip/hip_runtime.h>
#include <hip/hip_bf16.h>
#include <stdint.h>

using bf16 = __hip_bfloat16;
typedef __attribute__((ext_vector_type(8))) short short8;
typedef __attribute__((ext_vector_type(4))) float floatx4;

#define DL3 32768      // 32^3
#define BATCH 256
#define LDS_BYTES 131072   // 2 x 64KB bf16 state buffers

// LDS swizzle (involution): bank bits 4,5 ^= byte bits 7,8; bits 5,6 ^= bits 13,14.
// Read side (byte = kc*2048 + f*64 + quad*16): bits7,8 = f1,f2 (lane-varying),
// bits13,14 = kc2,kc3 (uniform). Write side (byte = f*2048 + n*2): bits7,8 = n6,n7
// (uniform), bits13,14 = f2,f3 = quad (spreads quads across banks).
__device__ __forceinline__ int swz(int b) {
  return b ^ ((((b) >> 7) & 3) << 4) ^ ((((b) >> 13) & 3) << 5);
}

// Fused prep: nodes (fp32) -> nodeTf (bf16, frag-major), one pass, 33KB LDS.
// nodeTf[i][kc][nt][lane(l16,q)][e] = B[n=nt*16+l16][k=kc*32+q*8+e]
//   where B[n][k] = node[i][u*32+v][n], k=v*32+u  =>  v=kc, u=q*8+e:
//   value = node[i][(q*8+e)*32+kc][n]      [same math as verified 2-pass prep]
__global__ __launch_bounds__(256) void prep_frag2(const float* __restrict__ nodes,
                                                  bf16* __restrict__ nodeTf) {
  int id = blockIdx.x;             // i*32 + kc
  int kc = id & 31, i = id >> 5;
  __shared__ bf16 sb[32][514];     // [u][n-local], +2 pad (row stride 1028B = bank+1)
  const float* base = nodes + (size_t)i * 1048576 + (size_t)kc * 1024;
  bf16* dst = nodeTf + (size_t)i * 1048576 + (size_t)kc * 32768;
  int t = threadIdx.x;
#pragma unroll 1
  for (int np = 0; np < 2; ++np) {   // n-half pass: n in [np*512, np*512+512)
    // read 32 rows x 512 floats (coalesced float4), convert to bf16 in sb
#pragma unroll
    for (int c = 0; c < 16; ++c) {
      int g4 = c * 256 + t;
      int u = g4 >> 7, c4 = g4 & 127;      // 128 float4 per row-half
      floatx4 v4 = *(const floatx4*)(base + (size_t)u * 32768 + np * 512 + c4 * 4);
      bf16* row = &sb[u][c4 * 4];
      row[0] = __float2bfloat16(v4[0]);
      row[1] = __float2bfloat16(v4[1]);
      row[2] = __float2bfloat16(v4[2]);
      row[3] = __float2bfloat16(v4[3]);
    }
    __syncthreads();
    // write 32 nt-granules of this half (coalesced 16B/lane)
#pragma unroll
    for (int c = 0; c < 8; ++c) {
      int g = c * 256 + t;
      int lane = g & 63, ntl = g >> 6;
      int l16 = lane & 15, q = lane >> 4;
      short8 vv;
#pragma unroll
      for (int e = 0; e < 8; ++e)
        vv[e] = *(const short*)&sb[q * 8 + e][ntl * 16 + l16];
      int nt = np * 32 + ntl;
      *(short8*)(dst + (size_t)nt * 512 + lane * 8) = vv;
    }
    __syncthreads();   // sb free for pass 2
  }
}

#define LDB(buf, kc_) { const char* _p = Bs + (size_t)(kc_) * 65536;          \
  _Pragma("unroll") for (int _j = 0; _j < 4; ++_j)                            \
    buf[_j] = *(const short8*)(_p + _j * 1024); }

#define LDA(af_, kc_) { _Pragma("unroll") for (int _i = 0; _i < 2; ++_i) {    \
  int _a = aLow[_i] + (kc_) * 2048; _a ^= ((_a >> 13) & 3) << 5;              \
  af_[_i] = *(const short8*)(sIn + _a); } }

#define MM(buf, af_) { _Pragma("unroll") for (int _i = 0; _i < 2; ++_i)       \
  _Pragma("unroll") for (int _j = 0; _j < 4; ++_j)                            \
    acc[_i][_j] = __builtin_amdgcn_mfma_f32_16x16x32_bf16(af_[_i], buf[_j], acc[_i][_j], 0, 0, 0); }

// Batch-resident chain: one block = one batch element, all 6 steps.
// 16 waves (1024 thr) at <=128 VGPR -> 4 waves/SIMD: L2-load latency hidden by
// TLP (no compiler-pipelining dependence). Wave w owns n in [w*64, w*64+64).
// State ping-pongs between two 64KB swizzled LDS buffers; B streams coalesced
// from L2 (frag-major nodeTf) via a depth-2 register ring.
__global__ __launch_bounds__(1024, 4) void entangler_batch(
    const float* __restrict__ x, const bf16* __restrict__ nodeTf,
    float* __restrict__ out, const float* __restrict__ bias) {
  extern __shared__ char smem[];
  char* st0 = smem;
  char* st1 = smem + 65536;

  const int t = threadIdx.x;
  const int lane = t & 63;
  const int lane16 = lane & 15, quad = lane >> 4;
  const int w = t >> 6;            // 0..15
  const int b = blockIdx.x;

  // ---- init: state0 logical byte (v*2048 + f*64 + u*2) <- x[b][u*1024+v*32+f]
  const float* xb = x + (size_t)b * DL3;
#pragma unroll
  for (int it = 0; it < 8; ++it) {
    int flat = it * 1024 + t;
    floatx4 vx = *(const floatx4*)(xb + flat * 4);
    int e0 = flat * 4;
    int f = e0 & 31, v = (e0 >> 5) & 31, u = e0 >> 10;
#pragma unroll
    for (int e = 0; e < 4; ++e) {
      int byte = v * 2048 + (f + e) * 64 + u * 2;
      *(bf16*)(st0 + swz(byte)) = __float2bfloat16(vx[e]);
    }
  }

  // A-frag low address (f*64 + quad*16, bit7,8 swizzle term folded in; the
  // kc-dependent bit13,14 term is applied per use in LDA).
  int aLow[2];
#pragma unroll
  for (int i2 = 0; i2 < 2; ++i2) {
    int bb = (i2 * 16 + lane16) * 64 + quad * 16;
    aLow[i2] = bb ^ (((bb >> 7) & 3) << 4);
  }

  // per-thread coalesced B base: granule (nt = w*4 + j, lane), 16B/lane
  const char* Bb = (const char*)nodeTf + (size_t)(w * 4096) + (size_t)(lane * 16);

  char* sIn = st0;
  char* sOut = st1;
  __syncthreads();   // init visible to all waves

#pragma unroll 1
  for (int s = 0; s < 6; ++s) {
    const char* Bs = Bb + (size_t)s * 2097152;

    floatx4 acc[2][4];
#pragma unroll
    for (int i2 = 0; i2 < 2; ++i2)
#pragma unroll
      for (int j = 0; j < 4; ++j)
        acc[i2][j] = (floatx4){0.f, 0.f, 0.f, 0.f};

    short8 b0[4], b1[4], afE[2], afO[2];
    LDB(b0, 0);
#pragma unroll 1
    for (int kc = 0; kc < 32; kc += 2) {
      LDB(b1, kc + 1);                 // prefetch odd chunk
      LDA(afE, kc);
      MM(b0, afE);
      if (kc + 2 < 32) LDB(b0, kc + 2);  // prefetch next even chunk
      LDA(afO, kc + 1);
      MM(b1, afO);
    }

    if (s < 5) {
      // epilogue -> LDS out buffer, logical byte = f_out*2048 + n*2, swizzled.
      // C/D layout: col = lane&15, row = quad*4 + reg  [m89-verified]
#pragma unroll
      for (int i2 = 0; i2 < 2; ++i2) {
#pragma unroll
        for (int j = 0; j < 4; ++j) {
#pragma unroll
          for (int r = 0; r < 4; ++r) {
            int f = i2 * 16 + quad * 4 + r;
            int n = w * 64 + j * 16 + lane16;
            int byte = f * 2048 + n * 2;
            *(bf16*)(sOut + swz(byte)) = __float2bfloat16(acc[i2][j][r]);
          }
        }
      }
      __syncthreads();   // publish new state; old state free to overwrite
      char* tmp = sIn; sIn = sOut; sOut = tmp;
    } else {
      // FINAL: out[b][f*1024+n] = relu(acc + bias[f*1024+n]), fp32
      float* ob = out + (size_t)b * DL3;
#pragma unroll
      for (int i2 = 0; i2 < 2; ++i2) {
#pragma unroll
        for (int j = 0; j < 4; ++j) {
#pragma unroll
          for (int r = 0; r < 4; ++r) {
            int f = i2 * 16 + quad * 4 + r;
            int n = w * 64 + j * 16 + lane16;
            float v = acc[i2][j][r] + bias[f * 1024 + n];
            ob[f * 1024 + n] = fmaxf(v, 0.f);
          }
        }
      }
    }
  }
}

extern "C" void kernel_launch(void* const* d_in, const int* in_sizes, int n_in,
                              void* d_out, int out_size, void* d_ws, size_t ws_size,
                              hipStream_t stream) {
  const float* x     = (const float*)d_in[0];   // (256, 32768) fp32
  const float* nodes = (const float*)d_in[1];   // (6, 32,32,32,32) fp32
  const float* bias  = (const float*)d_in[2];   // (32768,) fp32
  float* out = (float*)d_out;                   // (256, 32768) fp32

  // ws layout: nodeTf 12MB only
  bf16* nodeTf = (bf16*)d_ws;

  static bool attr_done = false;
  if (!attr_done) {
    hipFuncSetAttribute((const void*)entangler_batch,
                        hipFuncAttributeMaxDynamicSharedMemorySize, LDS_BYTES);
    attr_done = true;
  }

  prep_frag2<<<dim3(6 * 32), dim3(256), 0, stream>>>(nodes, nodeTf);
  entangler_batch<<<dim3(BATCH), dim3(1024), LDS_BYTES, stream>>>(x, nodeTf, out, bias);
}

// Round 9
// 292.730 us; speedup vs baseline: 1.0503x; 1.0503x over previous
//
#include <hip/hip_runtime.h>
#include <hip/hip_bf16.h>
#include <stdint.h>

using bf16 = __hip_bfloat16;
typedef __attribute__((ext_vector_type(8))) short short8;
typedef __attribute__((ext_vector_type(4))) float floatx4;

#define DL3 32768      // 32^3
#define BATCH 256
#define LDS_BYTES 131072   // 2 x 64KB bf16 state buffers

// LDS swizzle (involution): bank bits 4,5 ^= byte bits 7,8; bits 5,6 ^= bits 13,14.
__device__ __forceinline__ int swz(int b) {
  return b ^ ((((b) >> 7) & 3) << 4) ^ ((((b) >> 13) & 3) << 5);
}

// Fused prep (round-8 verified): nodes (fp32) -> nodeTf (bf16, frag-major).
// nodeTf[i][kc][nt][lane(l16,q)][e] = B[n=nt*16+l16][k=kc*32+q*8+e],
//   B[n][k] = node[i][u*32+v][n], k=v*32+u  =>  value = node[i][(q*8+e)*32+kc][n]
__global__ __launch_bounds__(256) void prep_frag2(const float* __restrict__ nodes,
                                                  bf16* __restrict__ nodeTf) {
  int id = blockIdx.x;             // i*32 + kc
  int kc = id & 31, i = id >> 5;
  __shared__ bf16 sb[32][514];     // +2 pad
  const float* base = nodes + (size_t)i * 1048576 + (size_t)kc * 1024;
  bf16* dst = nodeTf + (size_t)i * 1048576 + (size_t)kc * 32768;
  int t = threadIdx.x;
#pragma unroll 1
  for (int np = 0; np < 2; ++np) {   // n-half pass
#pragma unroll
    for (int c = 0; c < 16; ++c) {
      int g4 = c * 256 + t;
      int u = g4 >> 7, c4 = g4 & 127;
      floatx4 v4 = *(const floatx4*)(base + (size_t)u * 32768 + np * 512 + c4 * 4);
      bf16* row = &sb[u][c4 * 4];
      row[0] = __float2bfloat16(v4[0]);
      row[1] = __float2bfloat16(v4[1]);
      row[2] = __float2bfloat16(v4[2]);
      row[3] = __float2bfloat16(v4[3]);
    }
    __syncthreads();
#pragma unroll
    for (int c = 0; c < 8; ++c) {
      int g = c * 256 + t;
      int lane = g & 63, ntl = g >> 6;
      int l16 = lane & 15, q = lane >> 4;
      short8 vv;
#pragma unroll
      for (int e = 0; e < 8; ++e)
        vv[e] = *(const short*)&sb[q * 8 + e][ntl * 16 + l16];
      int nt = np * 32 + ntl;
      *(short8*)(dst + (size_t)nt * 512 + lane * 8) = vv;
    }
    __syncthreads();
  }
}

#define SB0 __builtin_amdgcn_sched_barrier(0);

#define LDB(buf, kc_) { const char* _p = Bs + (size_t)(kc_) * 65536;          \
  _Pragma("unroll") for (int _j = 0; _j < 8; ++_j)                            \
    buf[_j] = *(const short8*)(_p + _j * 1024); }

#define LDA(af_, kc_) { _Pragma("unroll") for (int _i = 0; _i < 2; ++_i) {    \
  int _a = aLow[_i] + (kc_) * 2048; _a ^= ((_a >> 13) & 3) << 5;              \
  af_[_i] = *(const short8*)(sIn + _a); } }

#define MM(buf, af_) { _Pragma("unroll") for (int _i = 0; _i < 2; ++_i)       \
  _Pragma("unroll") for (int _j = 0; _j < 8; ++_j)                            \
    acc[_i][_j] = __builtin_amdgcn_mfma_f32_16x16x32_bf16(af_[_i], buf[_j], acc[_i][_j], 0, 0, 0); }

// Batch-resident chain (round-6 structure): one block = one batch element,
// 8 waves, wave w owns n in [w*128, w*128+128). State ping-pongs between two
// 64KB swizzled LDS buffers. B streams coalesced from L2 via a 4-slot register
// ring; sched_barrier(0) after each issue cluster pins the 3-body prefetch
// distance (~280cyc > L2 latency) so the compiler cannot sink the loads.
__global__ __launch_bounds__(512, 2) void entangler_batch(
    const float* __restrict__ x, const bf16* __restrict__ nodeTf,
    float* __restrict__ out, const float* __restrict__ bias) {
  extern __shared__ char smem[];
  char* st0 = smem;
  char* st1 = smem + 65536;

  const int t = threadIdx.x;
  const int lane = t & 63;
  const int lane16 = lane & 15, quad = lane >> 4;
  const int w = t >> 6;            // 0..7
  const int b = blockIdx.x;

  // ---- init: state0 logical byte (v*2048 + f*64 + u*2) <- x[b][u*1024+v*32+f]
  const float* xb = x + (size_t)b * DL3;
#pragma unroll
  for (int it = 0; it < 16; ++it) {
    int flat = it * 512 + t;
    floatx4 vx = *(const floatx4*)(xb + flat * 4);
    int e0 = flat * 4;
    int f = e0 & 31, v = (e0 >> 5) & 31, u = e0 >> 10;
#pragma unroll
    for (int e = 0; e < 4; ++e) {
      int byte = v * 2048 + (f + e) * 64 + u * 2;
      *(bf16*)(st0 + swz(byte)) = __float2bfloat16(vx[e]);
    }
  }

  // A-frag low address (f*64 + quad*16, bit7,8 swizzle folded; kc term in LDA)
  int aLow[2];
#pragma unroll
  for (int i2 = 0; i2 < 2; ++i2) {
    int bb = (i2 * 16 + lane16) * 64 + quad * 16;
    aLow[i2] = bb ^ (((bb >> 7) & 3) << 4);
  }

  // per-thread coalesced B base: granule (nt = w*8 + j, lane), 16B/lane
  const char* Bb = (const char*)nodeTf + (size_t)(w * 8192) + (size_t)(lane * 16);

  char* sIn = st0;
  char* sOut = st1;
  __syncthreads();   // init visible to all waves

#pragma unroll 1
  for (int s = 0; s < 6; ++s) {
    const char* Bs = Bb + (size_t)s * 2097152;

    floatx4 acc[2][8];
#pragma unroll
    for (int i2 = 0; i2 < 2; ++i2)
#pragma unroll
      for (int j = 0; j < 8; ++j)
        acc[i2][j] = (floatx4){0.f, 0.f, 0.f, 0.f};

    short8 q0[8], q1[8], q2[8], q3[8], afE[2], afO[2];
    // prologue: bodies 0,1,2 in flight (24 loads)
    LDB(q0, 0) LDB(q1, 1) LDB(q2, 2)
    SB0
    LDA(afE, 0);

#pragma unroll 1
    for (int kc0 = 0; kc0 < 28; kc0 += 4) {
      LDB(q3, kc0 + 3) SB0 LDA(afO, kc0 + 1) MM(q0, afE)
      LDB(q0, kc0 + 4) SB0 LDA(afE, kc0 + 2) MM(q1, afO)
      LDB(q1, kc0 + 5) SB0 LDA(afO, kc0 + 3) MM(q2, afE)
      LDB(q2, kc0 + 6) SB0 LDA(afE, kc0 + 4) MM(q3, afO)
    }
    // tail: kc = 28..31 (one remaining load: body 31)
    LDB(q3, 31) SB0 LDA(afO, 29) MM(q0, afE)
    LDA(afE, 30) MM(q1, afO)
    LDA(afO, 31) MM(q2, afE)
    MM(q3, afO)

    if (s < 5) {
      // epilogue -> LDS out buffer, logical byte = f_out*2048 + n*2, swizzled.
      // C/D layout: col = lane&15, row = quad*4 + reg  [m89-verified]
#pragma unroll
      for (int i2 = 0; i2 < 2; ++i2) {
#pragma unroll
        for (int j = 0; j < 8; ++j) {
#pragma unroll
          for (int r = 0; r < 4; ++r) {
            int f = i2 * 16 + quad * 4 + r;
            int n = w * 128 + j * 16 + lane16;
            int byte = f * 2048 + n * 2;
            *(bf16*)(sOut + swz(byte)) = __float2bfloat16(acc[i2][j][r]);
          }
        }
      }
      __syncthreads();   // publish new state; old state free to overwrite
      char* tmp = sIn; sIn = sOut; sOut = tmp;
    } else {
      // FINAL: out[b][f*1024+n] = relu(acc + bias[f*1024+n]), fp32
      float* ob = out + (size_t)b * DL3;
#pragma unroll
      for (int i2 = 0; i2 < 2; ++i2) {
#pragma unroll
        for (int j = 0; j < 8; ++j) {
#pragma unroll
          for (int r = 0; r < 4; ++r) {
            int f = i2 * 16 + quad * 4 + r;
            int n = w * 128 + j * 16 + lane16;
            float v = acc[i2][j][r] + bias[f * 1024 + n];
            ob[f * 1024 + n] = fmaxf(v, 0.f);
          }
        }
      }
    }
  }
}

extern "C" void kernel_launch(void* const* d_in, const int* in_sizes, int n_in,
                              void* d_out, int out_size, void* d_ws, size_t ws_size,
                              hipStream_t stream) {
  const float* x     = (const float*)d_in[0];   // (256, 32768) fp32
  const float* nodes = (const float*)d_in[1];   // (6, 32,32,32,32) fp32
  const float* bias  = (const float*)d_in[2];   // (32768,) fp32
  float* out = (float*)d_out;                   // (256, 32768) fp32

  // ws layout: nodeTf 12MB only
  bf16* nodeTf = (bf16*)d_ws;

  static bool attr_done = false;
  if (!attr_done) {
    hipFuncSetAttribute((const void*)entangler_batch,
                        hipFuncAttributeMaxDynamicSharedMemorySize, LDS_BYTES);
    attr_done = true;
  }

  prep_frag2<<<dim3(6 * 32), dim3(256), 0, stream>>>(nodes, nodeTf);
  entangler_batch<<<dim3(BATCH), dim3(512), LDS_BYTES, stream>>>(x, nodeTf, out, bias);
}

// Round 10
// 292.438 us; speedup vs baseline: 1.0513x; 1.0010x over previous
//
#include <hip/hip_runtime.h>
#include <hip/hip_bf16.h>
#include <stdint.h>

using bf16 = __hip_bfloat16;
typedef __attribute__((ext_vector_type(8))) short short8;
typedef __attribute__((ext_vector_type(4))) float floatx4;

#define DL3 32768      // 32^3
#define BATCH 256
#define LDS_BYTES 131072   // 2 x 64KB bf16 state buffers

// LDS swizzle (involution): bank bits 4,5 ^= byte bits 7,8; bits 5,6 ^= bits 13,14.
__device__ __forceinline__ int swz(int b) {
  return b ^ ((((b) >> 7) & 3) << 4) ^ ((((b) >> 13) & 3) << 5);
}

// Fused prep (round-8 verified): nodes (fp32) -> nodeTf (bf16, frag-major).
// nodeTf[i][kc][nt][lane(l16,q)][e] = B[n=nt*16+l16][k=kc*32+q*8+e],
//   B[n][k] = node[i][u*32+v][n], k=v*32+u  =>  value = node[i][(q*8+e)*32+kc][n]
__global__ __launch_bounds__(256) void prep_frag2(const float* __restrict__ nodes,
                                                  bf16* __restrict__ nodeTf) {
  int id = blockIdx.x;             // i*32 + kc
  int kc = id & 31, i = id >> 5;
  __shared__ bf16 sb[32][514];     // +2 pad
  const float* base = nodes + (size_t)i * 1048576 + (size_t)kc * 1024;
  bf16* dst = nodeTf + (size_t)i * 1048576 + (size_t)kc * 32768;
  int t = threadIdx.x;
#pragma unroll 1
  for (int np = 0; np < 2; ++np) {   // n-half pass
#pragma unroll
    for (int c = 0; c < 16; ++c) {
      int g4 = c * 256 + t;
      int u = g4 >> 7, c4 = g4 & 127;
      floatx4 v4 = *(const floatx4*)(base + (size_t)u * 32768 + np * 512 + c4 * 4);
      bf16* row = &sb[u][c4 * 4];
      row[0] = __float2bfloat16(v4[0]);
      row[1] = __float2bfloat16(v4[1]);
      row[2] = __float2bfloat16(v4[2]);
      row[3] = __float2bfloat16(v4[3]);
    }
    __syncthreads();
#pragma unroll
    for (int c = 0; c < 8; ++c) {
      int g = c * 256 + t;
      int lane = g & 63, ntl = g >> 6;
      int l16 = lane & 15, q = lane >> 4;
      short8 vv;
#pragma unroll
      for (int e = 0; e < 8; ++e)
        vv[e] = *(const short*)&sb[q * 8 + e][ntl * 16 + l16];
      int nt = np * 32 + ntl;
      *(short8*)(dst + (size_t)nt * 512 + lane * 8) = vv;
    }
    __syncthreads();
  }
}

#define SB0 __builtin_amdgcn_sched_barrier(0);

#define LDB(buf, kc_) { const char* _p = Bs + (size_t)(kc_) * 65536;          \
  _Pragma("unroll") for (int _j = 0; _j < 8; ++_j)                            \
    buf[_j] = *(const short8*)(_p + _j * 1024); }

#define LDA(af_, kc_) { _Pragma("unroll") for (int _i = 0; _i < 2; ++_i) {    \
  int _a = aLow[_i] + (kc_) * 2048; _a ^= ((_a >> 13) & 3) << 5;              \
  af_[_i] = *(const short8*)(sIn + _a); } }

#define MM(buf, af_) { _Pragma("unroll") for (int _i = 0; _i < 2; ++_i)       \
  _Pragma("unroll") for (int _j = 0; _j < 8; ++_j)                            \
    acc[_i][_j] = __builtin_amdgcn_mfma_f32_16x16x32_bf16(af_[_i], buf[_j], acc[_i][_j], 0, 0, 0); }

// Batch-resident chain: one block = one batch element, 8 waves, wave w owns
// n in [w*128, w*128+128). State ping-pongs between two 64KB swizzled LDS
// buffers. B streams coalesced from L2 via a 4-slot register ring; SB0 pins
// the 3-body prefetch distance. amdgpu_waves_per_eu(2,2) caps the scheduler's
// occupancy target at the real (LDS-bound) 2 waves/EU so the ring gets the
// full 256-VGPR budget instead of spilling to meet a phantom 128-VGPR tier.
__global__ __launch_bounds__(512)
__attribute__((amdgpu_waves_per_eu(2, 2)))
void entangler_batch(
    const float* __restrict__ x, const bf16* __restrict__ nodeTf,
    float* __restrict__ out, const float* __restrict__ bias) {
  extern __shared__ char smem[];
  char* st0 = smem;
  char* st1 = smem + 65536;

  const int t = threadIdx.x;
  const int lane = t & 63;
  const int lane16 = lane & 15, quad = lane >> 4;
  const int w = t >> 6;            // 0..7
  const int b = blockIdx.x;

  // ---- init: state0 logical byte (v*2048 + f*64 + u*2) <- x[b][u*1024+v*32+f]
  const float* xb = x + (size_t)b * DL3;
#pragma unroll
  for (int it = 0; it < 16; ++it) {
    int flat = it * 512 + t;
    floatx4 vx = *(const floatx4*)(xb + flat * 4);
    int e0 = flat * 4;
    int f = e0 & 31, v = (e0 >> 5) & 31, u = e0 >> 10;
#pragma unroll
    for (int e = 0; e < 4; ++e) {
      int byte = v * 2048 + (f + e) * 64 + u * 2;
      *(bf16*)(st0 + swz(byte)) = __float2bfloat16(vx[e]);
    }
  }

  // A-frag low address (f*64 + quad*16, bit7,8 swizzle folded; kc term in LDA)
  int aLow[2];
#pragma unroll
  for (int i2 = 0; i2 < 2; ++i2) {
    int bb = (i2 * 16 + lane16) * 64 + quad * 16;
    aLow[i2] = bb ^ (((bb >> 7) & 3) << 4);
  }

  // per-thread coalesced B base: granule (nt = w*8 + j, lane), 16B/lane
  const char* Bb = (const char*)nodeTf + (size_t)(w * 8192) + (size_t)(lane * 16);

  char* sIn = st0;
  char* sOut = st1;
  __syncthreads();   // init visible to all waves

#pragma unroll 1
  for (int s = 0; s < 6; ++s) {
    const char* Bs = Bb + (size_t)s * 2097152;

    floatx4 acc[2][8];
#pragma unroll
    for (int i2 = 0; i2 < 2; ++i2)
#pragma unroll
      for (int j = 0; j < 8; ++j)
        acc[i2][j] = (floatx4){0.f, 0.f, 0.f, 0.f};

    short8 q0[8], q1[8], q2[8], q3[8], afE[2], afO[2];
    // prologue: bodies 0,1,2 in flight (24 loads)
    LDB(q0, 0) LDB(q1, 1) LDB(q2, 2)
    SB0
    LDA(afE, 0);

#pragma unroll 1
    for (int kc0 = 0; kc0 < 28; kc0 += 4) {
      LDB(q3, kc0 + 3) SB0 LDA(afO, kc0 + 1) MM(q0, afE)
      LDB(q0, kc0 + 4) SB0 LDA(afE, kc0 + 2) MM(q1, afO)
      LDB(q1, kc0 + 5) SB0 LDA(afO, kc0 + 3) MM(q2, afE)
      LDB(q2, kc0 + 6) SB0 LDA(afE, kc0 + 4) MM(q3, afO)
    }
    // tail: kc = 28..31 (one remaining load: body 31)
    LDB(q3, 31) SB0 LDA(afO, 29) MM(q0, afE)
    LDA(afE, 30) MM(q1, afO)
    LDA(afO, 31) MM(q2, afE)
    MM(q3, afO)

    if (s < 5) {
      // epilogue -> LDS out buffer, logical byte = f_out*2048 + n*2, swizzled.
      // C/D layout: col = lane&15, row = quad*4 + reg  [m89-verified]
#pragma unroll
      for (int i2 = 0; i2 < 2; ++i2) {
#pragma unroll
        for (int j = 0; j < 8; ++j) {
#pragma unroll
          for (int r = 0; r < 4; ++r) {
            int f = i2 * 16 + quad * 4 + r;
            int n = w * 128 + j * 16 + lane16;
            int byte = f * 2048 + n * 2;
            *(bf16*)(sOut + swz(byte)) = __float2bfloat16(acc[i2][j][r]);
          }
        }
      }
      __syncthreads();   // publish new state; old state free to overwrite
      char* tmp = sIn; sIn = sOut; sOut = tmp;
    } else {
      // FINAL: out[b][f*1024+n] = relu(acc + bias[f*1024+n]), fp32
      float* ob = out + (size_t)b * DL3;
#pragma unroll
      for (int i2 = 0; i2 < 2; ++i2) {
#pragma unroll
        for (int j = 0; j < 8; ++j) {
#pragma unroll
          for (int r = 0; r < 4; ++r) {
            int f = i2 * 16 + quad * 4 + r;
            int n = w * 128 + j * 16 + lane16;
            float v = acc[i2][j][r] + bias[f * 1024 + n];
            ob[f * 1024 + n] = fmaxf(v, 0.f);
          }
        }
      }
    }
  }
}

extern "C" void kernel_launch(void* const* d_in, const int* in_sizes, int n_in,
                              void* d_out, int out_size, void* d_ws, size_t ws_size,
                              hipStream_t stream) {
  const float* x     = (const float*)d_in[0];   // (256, 32768) fp32
  const float* nodes = (const float*)d_in[1];   // (6, 32,32,32,32) fp32
  const float* bias  = (const float*)d_in[2];   // (32768,) fp32
  float* out = (float*)d_out;                   // (256, 32768) fp32

  // ws layout: nodeTf 12MB only
  bf16* nodeTf = (bf16*)d_ws;

  static bool attr_done = false;
  if (!attr_done) {
    hipFuncSetAttribute((const void*)entangler_batch,
                        hipFuncAttributeMaxDynamicSharedMemorySize, LDS_BYTES);
    attr_done = true;
  }

  prep_frag2<<<dim3(6 * 32), dim3(256), 0, stream>>>(nodes, nodeTf);
  entangler_batch<<<dim3(BATCH), dim3(512), LDS_BYTES, stream>>>(x, nodeTf, out, bias);
}